// Round 7
// baseline (455.326 us; speedup 1.0000x reference)
//
#include <hip/hip_runtime.h>
#include <stdint.h>

#pragma clang fp contract(off)

#define Bn 2
#define Hn 512
#define Wn 512
#define Dn 128
#define HW (Hn * Wn)            // 262144
#define NRAY (Bn * HW)          // 524288
#define NSTEP 180
#define DTC 0.02f
#define D3 (Dn * Dn * Dn)
#define NBLK (NRAY / 256)       // 2048 march blocks

// ws layout (floats): [2*bid] = block max(len), [2*bid+1] = block min(len).
// Written by march every iteration before finalize reads -> poison-proof.

typedef float f2 __attribute__((ext_vector_type(2)));

// step = 0.02 * e^(0.01*sqrt2*pw) = exp2(pw*KEXP + LOG2DT)
#define KEXP  ((float)(0.01 * (double)1.41421354f * 1.4426950408889634))
#define LOG2DT (-5.643856189774724f)   // log2(0.02)

// guaranteed 1-inst rotate: rotl(x,n) == v_alignbit_b32(x, x, 32-n)
__device__ __forceinline__ uint32_t rotl32(uint32_t x, int n) {
    return __builtin_amdgcn_alignbit(x, x, 32u - (uint32_t)n);
}

// JAX threefry2x32 (20 rounds, 5 groups of 4) — single-stream
__device__ __forceinline__ void tf2x32(uint32_t k0, uint32_t k1,
                                       uint32_t& x0, uint32_t& x1) {
    uint32_t k2 = k0 ^ k1 ^ 0x1BD11BDAu;
    x0 += k0; x1 += k1;
    x0 += x1; x1 = rotl32(x1, 13); x1 ^= x0;
    x0 += x1; x1 = rotl32(x1, 15); x1 ^= x0;
    x0 += x1; x1 = rotl32(x1, 26); x1 ^= x0;
    x0 += x1; x1 = rotl32(x1, 6);  x1 ^= x0;
    x0 += k1; x1 += k2 + 1u;
    x0 += x1; x1 = rotl32(x1, 17); x1 ^= x0;
    x0 += x1; x1 = rotl32(x1, 29); x1 ^= x0;
    x0 += x1; x1 = rotl32(x1, 16); x1 ^= x0;
    x0 += x1; x1 = rotl32(x1, 24); x1 ^= x0;
    x0 += k2; x1 += k0 + 2u;
    x0 += x1; x1 = rotl32(x1, 13); x1 ^= x0;
    x0 += x1; x1 = rotl32(x1, 15); x1 ^= x0;
    x0 += x1; x1 = rotl32(x1, 26); x1 ^= x0;
    x0 += x1; x1 = rotl32(x1, 6);  x1 ^= x0;
    x0 += k0; x1 += k1 + 3u;
    x0 += x1; x1 = rotl32(x1, 17); x1 ^= x0;
    x0 += x1; x1 = rotl32(x1, 29); x1 ^= x0;
    x0 += x1; x1 = rotl32(x1, 16); x1 ^= x0;
    x0 += x1; x1 = rotl32(x1, 24); x1 ^= x0;
    x0 += k1; x1 += k2 + 4u;
    x0 += x1; x1 = rotl32(x1, 13); x1 ^= x0;
    x0 += x1; x1 = rotl32(x1, 15); x1 ^= x0;
    x0 += x1; x1 = rotl32(x1, 26); x1 ^= x0;
    x0 += x1; x1 = rotl32(x1, 6);  x1 ^= x0;
    x0 += k2; x1 += k0 + 5u;
}

// jax_threefry_partitionable random_bits: element i -> counter (0,i), o0^o1.
__device__ __forceinline__ uint32_t pbits(uint32_t k0, uint32_t k1, uint32_t i) {
    uint32_t x0 = 0u, x1 = i;
    tf2x32(k0, k1, x0, x1);
    return x0 ^ x1;
}

// Fast erfinv core: returns p*x.
__device__ __forceinline__ float erfinv_px(float x) {
    #pragma clang fp contract(off)
    float a = x * x;
    float w = -__logf(1.0f - a);
    float p;
    if (w < 5.0f) {
        w = w - 2.5f;
        p = 2.81022636e-08f;
        p = fmaf(p, w, 3.43273939e-07f);
        p = fmaf(p, w, -3.5233877e-06f);
        p = fmaf(p, w, -4.39150654e-06f);
        p = fmaf(p, w, 0.00021858087f);
        p = fmaf(p, w, -0.00125372503f);
        p = fmaf(p, w, -0.00417768164f);
        p = fmaf(p, w, 0.246640727f);
        p = fmaf(p, w, 1.50140941f);
    } else {
        w = sqrtf(w) - 3.0f;
        p = -0.000200214257f;
        p = fmaf(p, w, 0.000100950558f);
        p = fmaf(p, w, 0.00134934322f);
        p = fmaf(p, w, -0.00367342844f);
        p = fmaf(p, w, 0.00573950773f);
        p = fmaf(p, w, -0.0076224613f);
        p = fmaf(p, w, 0.00943887047f);
        p = fmaf(p, w, 1.00167406f);
        p = fmaf(p, w, 2.83297682f);
    }
    return p * x;
}

// noise->step. (bits>>9)|0x3f800000 == v_alignbit_b32(0x7f, bits, 9): 1 inst.
__device__ __forceinline__ float step_from_bits(uint32_t bits) {
    #pragma clang fp contract(off)
    float uf = __uint_as_float(__builtin_amdgcn_alignbit(0x7fu, bits, 9u));
    float uu = fmaxf(-0.99999994f, fmaf(uf, 2.0f, -3.0f));
    float pw = erfinv_px(uu);
    return __builtin_amdgcn_exp2f(fmaf(pw, KEXP, LOG2DT));
}

// 4-chain threefry: steps for 4 consecutive per-step keys, same counter idx.
// Each chain is bitwise identical to tf2x32 (initial injection folded into
// the state init: x0 = 0 + k0, x1 = idx + k1). ILP=4 breaks the serial
// add->alignbit->xor dependence chain.
__device__ __forceinline__ void steps4(uint2 kk0, uint2 kk1,
                                       uint2 kk2, uint2 kk3,
                                       uint32_t idx, float s[4]) {
    uint32_t k0[4] = {kk0.x, kk1.x, kk2.x, kk3.x};
    uint32_t k1[4] = {kk0.y, kk1.y, kk2.y, kk3.y};
    uint32_t k2[4], x0[4], x1[4];
    #pragma unroll
    for (int c = 0; c < 4; ++c) {
        k2[c] = k0[c] ^ k1[c] ^ 0x1BD11BDAu;
        x0[c] = k0[c];            // 0 + k0
        x1[c] = idx + k1[c];      // idx + k1
    }
#define RND4(r) { _Pragma("unroll") for (int c = 0; c < 4; ++c) { \
        x0[c] += x1[c]; x1[c] = rotl32(x1[c], r); x1[c] ^= x0[c]; } }
#define INJ4(A, B, inc) { _Pragma("unroll") for (int c = 0; c < 4; ++c) { \
        x0[c] += A[c]; x1[c] += B[c] + inc; } }
    RND4(13) RND4(15) RND4(26) RND4(6)
    INJ4(k1, k2, 1u)
    RND4(17) RND4(29) RND4(16) RND4(24)
    INJ4(k2, k0, 2u)
    RND4(13) RND4(15) RND4(26) RND4(6)
    INJ4(k0, k1, 3u)
    RND4(17) RND4(29) RND4(16) RND4(24)
    INJ4(k1, k2, 4u)
    RND4(13) RND4(15) RND4(26) RND4(6)
    INJ4(k2, k0, 5u)
#undef RND4
#undef INJ4
    #pragma unroll
    for (int c = 0; c < 4; ++c) s[c] = step_from_bits(x0[c] ^ x1[c]);
}

// packed lerp: d = a + w*(b-a)  (identical arithmetic to all passing rounds)
__device__ __forceinline__ f2 plerp(f2 a, f2 b, f2 wv) {
    return __builtin_elementwise_fma(wv, b - a, a);
}

__global__ __launch_bounds__(256, 4) void march_kernel(
    const float* __restrict__ rot, const float* __restrict__ cpos,
    const float* __restrict__ focal, const float* __restrict__ pp,
    const float* __restrict__ tpl,
    const float* __restrict__ bg, float* __restrict__ out,
    float* __restrict__ wsf)
{
    #pragma clang fp contract(off)
    // Per-block RNG key table: fold_in(key(42), t) for t = 0..180.
    // 181 threefry evals per block = 0.4% of the per-ray RNG work.
    __shared__ uint2 skeys[181];
    {
        int t = threadIdx.x;
        if (t <= 180) {
            uint32_t x0 = 0u, x1 = (uint32_t)t;
            tf2x32(0u, 42u, x0, x1);
            skeys[t] = make_uint2(x0, x1);
        }
    }
    __syncthreads();

    const int idx = blockIdx.x * 256 + threadIdx.x;
    const int b = idx >> 18;          // / HW
    const int p = idx & (HW - 1);

    // ---- ray setup (trajectory-critical: separate roundings preserved) ----
    // pixel_coords[b,y,x] = (x,y) exactly (meshgrid of arange; ints <= 511
    // are exact in fp32) -> int convert is bit-identical to the pix[] load.
    float px = (float)(p & (Wn - 1));
    float py = (float)(p >> 9);
    float v0 = (px - pp[b * 2 + 0]) / focal[b * 2 + 0];
    float v1 = (py - pp[b * 2 + 1]) / focal[b * 2 + 1];
    const float* R = rot + b * 9;
    float rdx = (R[0] * v0 + R[3] * v1) + R[6];
    float rdy = (R[1] * v0 + R[4] * v1) + R[7];
    float rdz = (R[2] * v0 + R[5] * v1) + R[8];
    float nrm = sqrtf((rdx * rdx + rdy * rdy) + rdz * rdz);
    rdx = rdx / nrm; rdy = rdy / nrm; rdz = rdz / nrm;
    float cpx = cpos[b * 3 + 0], cpy = cpos[b * 3 + 1], cpz = cpos[b * 3 + 2];

    float t1x = (-1.0f - cpx) / rdx, t2x = (1.0f - cpx) / rdx;
    float t1y = (-1.0f - cpy) / rdy, t2y = (1.0f - cpy) / rdy;
    float t1z = (-1.0f - cpz) / rdz, t2z = (1.0f - cpz) / rdz;
    float tmin = fmaxf(fminf(t1x, t2x), fmaxf(fminf(t1y, t2y), fminf(t1z, t2z)));
    float tmax = fminf(fmaxf(t1x, t2x), fminf(fmaxf(t1y, t2y), fmaxf(t1z, t2z)));
    bool hit = tmin < tmax;
    float t = fmaxf(hit ? tmin : 0.0f, 0.0f);

    // initial jitter: uniform [0,1) under fold_in(key,0), partitionable bits
    {
        uint2 k0 = skeys[0];
        uint32_t bits = pbits(k0.x, k0.y, (uint32_t)idx);
        float u = __uint_as_float(__builtin_amdgcn_alignbit(0x7fu, bits, 9u)) - 1.0f;
        u = fmaxf(0.0f, u);
        t = t - DTC * u;
    }

    float posx = cpx + rdx * t;
    float posy = cpy + rdy * t;
    float posz = cpz + rdz * t;

    float alpha = 0.0f, len = 0.0f;
    f2 acc_rg = {0.0f, 0.0f};
    float acc_b = 0.0f;
    bool entered = false;
    // A miss-ray only ever does len += step, identical to the tail body;
    // marking it done up-front lets all-miss waves skip the march loop
    // entirely (validated bit-exact earlier).
    bool done = !hit;

    int i = 0;
    if (!__all(done)) {
        // Chunked march: 4 steps per chunk from 4 interleaved threefry
        // chains (ILP-4), early-exit at chunk boundaries (bit-exact: a done
        // ray's sub-step degenerates to the tail body, only len += step).
        // Volume sampled directly from the SoA template: per corner, per
        // channel, one dwordx2 (x-pair) load. Same bytes as the old AoS
        // path; R5 proved march is insensitive to volume access pattern.
        const float* vc0 = tpl + (size_t)b * 4 * D3;
        const float* vc1 = vc0 + D3;
        const float* vc2 = vc0 + 2 * D3;
        const float* vc3 = vc0 + 3 * D3;
        while (i < NSTEP) {
            float s4[4];
            steps4(skeys[i + 1], skeys[i + 2], skeys[i + 3], skeys[i + 4],
                   (uint32_t)idx, s4);
            #pragma unroll
            for (int j = 0; j < 4; ++j) {
                float step = s4[j];
                float m = fmaxf(fmaxf(fabsf(posx), fabsf(posy)), fabsf(posz));
                bool valid = m < 1.0f;
                bool sampling = fmaxf(m, alpha) < 1.0f;

                float contrib = 0.0f;
                if (sampling) {
                    // pos in (-1,1) strictly => g in [0,127], no clamps needed
                    float gx = fmaf(posx, 63.5f, 63.5f);
                    float gy = fmaf(posy, 63.5f, 63.5f);
                    float gz = fmaf(posz, 63.5f, 63.5f);
                    float fx = floorf(gx), fy = floorf(gy), fz = floorf(gz);
                    float wx = gx - fx, wy = gy - fy, wz = gz - fz;
                    int ix0 = (int)fx, iy0 = (int)fy, iz0 = (int)fz;

                    // same clamps/weights as the validated packed path
                    int xs = min(ix0, Dn - 2);
                    float wxe = (ix0 < Dn - 1) ? wx : 1.0f;
                    int y0 = iy0, y1 = min(iy0 + 1, Dn - 1);
                    int z0 = iz0, z1 = min(iz0 + 1, Dn - 1);
                    int o00 = (z0 * Dn + y0) * Dn + xs;
                    int o01 = (z0 * Dn + y1) * Dn + xs;
                    int o10 = (z1 * Dn + y0) * Dn + xs;
                    int o11 = (z1 * Dn + y1) * Dn + xs;

                    // 16 dwordx2 loads: 4 corners x 4 channels (x-pairs)
                    f2 r00 = *(const f2*)(vc0 + o00), g00 = *(const f2*)(vc1 + o00);
                    f2 b00 = *(const f2*)(vc2 + o00), a00 = *(const f2*)(vc3 + o00);
                    f2 r01 = *(const f2*)(vc0 + o01), g01 = *(const f2*)(vc1 + o01);
                    f2 b01 = *(const f2*)(vc2 + o01), a01 = *(const f2*)(vc3 + o01);
                    f2 r10 = *(const f2*)(vc0 + o10), g10 = *(const f2*)(vc1 + o10);
                    f2 b10 = *(const f2*)(vc2 + o10), a10 = *(const f2*)(vc3 + o10);
                    f2 r11 = *(const f2*)(vc0 + o11), g11 = *(const f2*)(vc1 + o11);
                    f2 b11 = *(const f2*)(vc2 + o11), a11 = *(const f2*)(vc3 + o11);

                    // identical plerp chain (elementwise fma(w, hi-lo, lo))
                    f2 wxv = {wxe, wxe}, wyv = {wy, wy}, wzv = {wz, wz};
                    f2 c00rg = plerp((f2){r00.x, g00.x}, (f2){r00.y, g00.y}, wxv);
                    f2 c00ba = plerp((f2){b00.x, a00.x}, (f2){b00.y, a00.y}, wxv);
                    f2 c01rg = plerp((f2){r01.x, g01.x}, (f2){r01.y, g01.y}, wxv);
                    f2 c01ba = plerp((f2){b01.x, a01.x}, (f2){b01.y, a01.y}, wxv);
                    f2 c10rg = plerp((f2){r10.x, g10.x}, (f2){r10.y, g10.y}, wxv);
                    f2 c10ba = plerp((f2){b10.x, a10.x}, (f2){b10.y, a10.y}, wxv);
                    f2 c11rg = plerp((f2){r11.x, g11.x}, (f2){r11.y, g11.y}, wxv);
                    f2 c11ba = plerp((f2){b11.x, a11.x}, (f2){b11.y, a11.y}, wxv);
                    f2 c0rg = plerp(c00rg, c01rg, wyv);
                    f2 c0ba = plerp(c00ba, c01ba, wyv);
                    f2 c1rg = plerp(c10rg, c11rg, wyv);
                    f2 c1ba = plerp(c10ba, c11ba, wyv);
                    f2 srg = plerp(c0rg, c1rg, wzv);
                    f2 sba = plerp(c0ba, c1ba, wzv);

                    contrib = fminf(fmaf(sba.y, step, alpha), 1.0f) - alpha;
                    f2 cv = {contrib, contrib};
                    acc_rg = __builtin_elementwise_fma(srg, cv, acc_rg);
                    acc_b = fmaf(sba.x, contrib, acc_b);
                }
                alpha = alpha + contrib;
                if (contrib == 0.0f) len = len + step;
                posx = fmaf(rdx, step, posx);
                posy = fmaf(rdy, step, posy);
                posz = fmaf(rdz, step, posz);

                bool done_now = (alpha >= 1.0f) || (entered && !valid);
                entered = entered || valid;
                done = done || done_now;
            }
            i += 4;
            if (__all(done)) break;
        }
    }

    // tail: every remaining step has contrib == 0 -> only len accumulates.
    for (; i + 3 < NSTEP; i += 4) {
        float s4[4];
        steps4(skeys[i + 1], skeys[i + 2], skeys[i + 3], skeys[i + 4],
               (uint32_t)idx, s4);
        len = len + s4[0];
        len = len + s4[1];
        len = len + s4[2];
        len = len + s4[3];
    }
    for (; i < NSTEP; ++i) {
        uint2 kk = skeys[i + 1];
        len = len + step_from_bits(pbits(kk.x, kk.y, (uint32_t)idx));
    }

    // ---- epilogue: rgb + background blend, alpha, raw length ----
    size_t obase = (size_t)b * 3 * HW + p;
    out[obase]            = acc_rg.x + (1.0f - alpha) * fmaxf(bg[obase], 0.0f);
    out[obase + HW]       = acc_rg.y + (1.0f - alpha) * fmaxf(bg[obase + HW], 0.0f);
    out[obase + 2 * HW]   = acc_b   + (1.0f - alpha) * fmaxf(bg[obase + 2 * HW], 0.0f);
    out[(size_t)Bn * 3 * HW + (size_t)b * HW + p] = alpha;
    out[(size_t)Bn * 4 * HW + (size_t)b * HW + p] = len;

    // ---- block reduce min/max of len -> per-block slots (no atomics, no
    // ws init needed: every slot is written each iteration before finalize
    // reads it, so workspace poisoning is harmless) ----
    __shared__ float smax[256];
    __shared__ float smin[256];
    smax[threadIdx.x] = len;
    smin[threadIdx.x] = len;
    __syncthreads();
    for (int s = 128; s > 0; s >>= 1) {
        if (threadIdx.x < s) {
            smax[threadIdx.x] = fmaxf(smax[threadIdx.x], smax[threadIdx.x + s]);
            smin[threadIdx.x] = fminf(smin[threadIdx.x], smin[threadIdx.x + s]);
        }
        __syncthreads();
    }
    if (threadIdx.x == 0) {
        wsf[2 * blockIdx.x]     = smax[0];
        wsf[2 * blockIdx.x + 1] = smin[0];
    }
}

__global__ __launch_bounds__(256) void finalize_kernel(
    float* __restrict__ out, const float* __restrict__ wsf) {
    #pragma clang fp contract(off)
    // re-reduce the 2048 per-block (max,min) pairs (L2-resident, ~16 KB)
    __shared__ float smax[256];
    __shared__ float smin[256];
    float mx = 0.0f;            // len >= 0
    float mn = 3.402823466e+38f;
    for (int j = threadIdx.x; j < NBLK; j += 256) {
        mx = fmaxf(mx, wsf[2 * j]);
        mn = fminf(mn, wsf[2 * j + 1]);
    }
    smax[threadIdx.x] = mx;
    smin[threadIdx.x] = mn;
    __syncthreads();
    for (int s = 128; s > 0; s >>= 1) {
        if (threadIdx.x < s) {
            smax[threadIdx.x] = fmaxf(smax[threadIdx.x], smax[threadIdx.x + s]);
            smin[threadIdx.x] = fminf(smin[threadIdx.x], smin[threadIdx.x + s]);
        }
        __syncthreads();
    }
    mx = smax[0];
    mn = smin[0];

    int i = blockIdx.x * 256 + threadIdx.x;
    if (i >= NRAY) return;
    float a = out[(size_t)Bn * 3 * HW + i];
    size_t loff = (size_t)Bn * 4 * HW + i;
    float l = out[loff];
    out[loff] = (a * l) / (mx + mn);
}

extern "C" void kernel_launch(void* const* d_in, const int* in_sizes, int n_in,
                              void* d_out, int out_size, void* d_ws, size_t ws_size,
                              hipStream_t stream) {
    const float* rot   = (const float*)d_in[0];
    const float* cpos  = (const float*)d_in[1];
    const float* focal = (const float*)d_in[2];
    const float* pp    = (const float*)d_in[3];
    // d_in[4] (pixel_coords) is reconstructed exactly on-device; unused.
    const float* tpl   = (const float*)d_in[5];
    const float* bg    = (const float*)d_in[6];
    float* out = (float*)d_out;
    float* wsf = (float*)d_ws;

    hipLaunchKernelGGL(march_kernel, dim3(NBLK), dim3(256), 0, stream,
                       rot, cpos, focal, pp, tpl, bg, out, wsf);
    hipLaunchKernelGGL(finalize_kernel, dim3(NRAY / 256), dim3(256), 0, stream,
                       out, wsf);
}

// Round 9
// 418.955 us; speedup vs baseline: 1.0868x; 1.0868x over previous
//
#include <hip/hip_runtime.h>
#include <stdint.h>

#pragma clang fp contract(off)

#define Bn 2
#define Hn 512
#define Wn 512
#define Dn 128
#define HW (Hn * Wn)            // 262144
#define NRAY (Bn * HW)          // 524288
#define NSTEP 180
#define DTC 0.02f
#define D3 (Dn * Dn * Dn)
#define NBLK (NRAY / 256)       // 2048 march blocks

// ws layout (floats): [0..2*NBLK) = per-block (max,min) of len. All slots
// are written by march before finalize reads them -> workspace poisoning
// between iterations is harmless (no persistent state, no atomics).
// byte 32768+: AoS float4 volume (Bn*D3 voxels, 67 MB) when ws_size permits.
#define WS_AOS_BYTE_OFF 32768
#define WS_AOS_BYTES ((size_t)Bn * D3 * 16)

typedef float f2 __attribute__((ext_vector_type(2)));

// step = 0.02 * e^(0.01*sqrt2*pw) = exp2(pw*KEXP + LOG2DT)
#define KEXP  ((float)(0.01 * (double)1.41421354f * 1.4426950408889634))
#define LOG2DT (-5.643856189774724f)   // log2(0.02)

// guaranteed 1-inst rotate: rotl(x,n) == v_alignbit_b32(x, x, 32-n)
__device__ __forceinline__ uint32_t rotl32(uint32_t x, int n) {
    return __builtin_amdgcn_alignbit(x, x, 32u - (uint32_t)n);
}

// JAX threefry2x32 (20 rounds, 5 groups of 4) — single-stream
__device__ __forceinline__ void tf2x32(uint32_t k0, uint32_t k1,
                                       uint32_t& x0, uint32_t& x1) {
    uint32_t k2 = k0 ^ k1 ^ 0x1BD11BDAu;
    x0 += k0; x1 += k1;
    x0 += x1; x1 = rotl32(x1, 13); x1 ^= x0;
    x0 += x1; x1 = rotl32(x1, 15); x1 ^= x0;
    x0 += x1; x1 = rotl32(x1, 26); x1 ^= x0;
    x0 += x1; x1 = rotl32(x1, 6);  x1 ^= x0;
    x0 += k1; x1 += k2 + 1u;
    x0 += x1; x1 = rotl32(x1, 17); x1 ^= x0;
    x0 += x1; x1 = rotl32(x1, 29); x1 ^= x0;
    x0 += x1; x1 = rotl32(x1, 16); x1 ^= x0;
    x0 += x1; x1 = rotl32(x1, 24); x1 ^= x0;
    x0 += k2; x1 += k0 + 2u;
    x0 += x1; x1 = rotl32(x1, 13); x1 ^= x0;
    x0 += x1; x1 = rotl32(x1, 15); x1 ^= x0;
    x0 += x1; x1 = rotl32(x1, 26); x1 ^= x0;
    x0 += x1; x1 = rotl32(x1, 6);  x1 ^= x0;
    x0 += k0; x1 += k1 + 3u;
    x0 += x1; x1 = rotl32(x1, 17); x1 ^= x0;
    x0 += x1; x1 = rotl32(x1, 29); x1 ^= x0;
    x0 += x1; x1 = rotl32(x1, 16); x1 ^= x0;
    x0 += x1; x1 = rotl32(x1, 24); x1 ^= x0;
    x0 += k1; x1 += k2 + 4u;
    x0 += x1; x1 = rotl32(x1, 13); x1 ^= x0;
    x0 += x1; x1 = rotl32(x1, 15); x1 ^= x0;
    x0 += x1; x1 = rotl32(x1, 26); x1 ^= x0;
    x0 += x1; x1 = rotl32(x1, 6);  x1 ^= x0;
    x0 += k2; x1 += k0 + 5u;
}

// jax_threefry_partitionable random_bits: element i -> counter (0,i), o0^o1.
__device__ __forceinline__ uint32_t pbits(uint32_t k0, uint32_t k1, uint32_t i) {
    uint32_t x0 = 0u, x1 = i;
    tf2x32(k0, k1, x0, x1);
    return x0 ^ x1;
}

// Fast erfinv core: returns p*x.
__device__ __forceinline__ float erfinv_px(float x) {
    #pragma clang fp contract(off)
    float a = x * x;
    float w = -__logf(1.0f - a);
    float p;
    if (w < 5.0f) {
        w = w - 2.5f;
        p = 2.81022636e-08f;
        p = fmaf(p, w, 3.43273939e-07f);
        p = fmaf(p, w, -3.5233877e-06f);
        p = fmaf(p, w, -4.39150654e-06f);
        p = fmaf(p, w, 0.00021858087f);
        p = fmaf(p, w, -0.00125372503f);
        p = fmaf(p, w, -0.00417768164f);
        p = fmaf(p, w, 0.246640727f);
        p = fmaf(p, w, 1.50140941f);
    } else {
        w = sqrtf(w) - 3.0f;
        p = -0.000200214257f;
        p = fmaf(p, w, 0.000100950558f);
        p = fmaf(p, w, 0.00134934322f);
        p = fmaf(p, w, -0.00367342844f);
        p = fmaf(p, w, 0.00573950773f);
        p = fmaf(p, w, -0.0076224613f);
        p = fmaf(p, w, 0.00943887047f);
        p = fmaf(p, w, 1.00167406f);
        p = fmaf(p, w, 2.83297682f);
    }
    return p * x;
}

// noise->step. (bits>>9)|0x3f800000 == v_alignbit_b32(0x7f, bits, 9): 1 inst.
__device__ __forceinline__ float step_from_bits(uint32_t bits) {
    #pragma clang fp contract(off)
    float uf = __uint_as_float(__builtin_amdgcn_alignbit(0x7fu, bits, 9u));
    float uu = fmaxf(-0.99999994f, fmaf(uf, 2.0f, -3.0f));
    float pw = erfinv_px(uu);
    return __builtin_amdgcn_exp2f(fmaf(pw, KEXP, LOG2DT));
}

// 4-chain threefry: steps for 4 consecutive per-step keys, same counter idx.
// Each chain is bitwise identical to tf2x32 (initial injection folded into
// the state init). ILP=4 breaks the serial add->alignbit->xor chain.
__device__ __forceinline__ void steps4(uint2 kk0, uint2 kk1,
                                       uint2 kk2, uint2 kk3,
                                       uint32_t idx, float s[4]) {
    uint32_t k0[4] = {kk0.x, kk1.x, kk2.x, kk3.x};
    uint32_t k1[4] = {kk0.y, kk1.y, kk2.y, kk3.y};
    uint32_t k2[4], x0[4], x1[4];
    #pragma unroll
    for (int c = 0; c < 4; ++c) {
        k2[c] = k0[c] ^ k1[c] ^ 0x1BD11BDAu;
        x0[c] = k0[c];            // 0 + k0
        x1[c] = idx + k1[c];      // idx + k1
    }
#define RND4(r) { _Pragma("unroll") for (int c = 0; c < 4; ++c) { \
        x0[c] += x1[c]; x1[c] = rotl32(x1[c], r); x1[c] ^= x0[c]; } }
#define INJ4(A, B, inc) { _Pragma("unroll") for (int c = 0; c < 4; ++c) { \
        x0[c] += A[c]; x1[c] += B[c] + inc; } }
    RND4(13) RND4(15) RND4(26) RND4(6)
    INJ4(k1, k2, 1u)
    RND4(17) RND4(29) RND4(16) RND4(24)
    INJ4(k2, k0, 2u)
    RND4(13) RND4(15) RND4(26) RND4(6)
    INJ4(k0, k1, 3u)
    RND4(17) RND4(29) RND4(16) RND4(24)
    INJ4(k1, k2, 4u)
    RND4(13) RND4(15) RND4(26) RND4(6)
    INJ4(k2, k0, 5u)
#undef RND4
#undef INJ4
    #pragma unroll
    for (int c = 0; c < 4; ++c) s[c] = step_from_bits(x0[c] ^ x1[c]);
}

// packed lerp: d = a + w*(b-a)  (identical arithmetic to all passing rounds)
__device__ __forceinline__ f2 plerp(f2 a, f2 b, f2 wv) {
    return __builtin_elementwise_fma(wv, b - a, a);
}

// SoA (b,c,z,y,x) -> AoS float4 per voxel. AoS is structurally required:
// R7 measured +27% march time without it (TA request-count bound; 8x
// dwordx4 per sample is the ISA floor).
__global__ __launch_bounds__(256) void repack_kernel(
    const float* __restrict__ tpl, float4* __restrict__ aos) {
    int i = blockIdx.x * 256 + threadIdx.x;
    int b = i >> 21;                 // / D3 (D3 = 2^21)
    int v = i & (D3 - 1);
    const float* base = tpl + (size_t)b * 4 * D3 + v;
    float4 o;
    o.x = base[0];
    o.y = base[D3];
    o.z = base[2 * D3];
    o.w = base[3 * D3];
    aos[i] = o;
}

template <bool PACKED>
__global__ __launch_bounds__(256, 4) void march_kernel(
    const float* __restrict__ rot, const float* __restrict__ cpos,
    const float* __restrict__ focal, const float* __restrict__ pp,
    const float* __restrict__ tpl, const float4* __restrict__ aos,
    const float* __restrict__ bg, float* __restrict__ out,
    float* __restrict__ wsf)
{
    #pragma clang fp contract(off)
    // Per-block RNG key table: fold_in(key(42), t), t = 0..180 (validated
    // R6: 181 threefry evals/block = 0.4% of per-ray RNG work).
    __shared__ uint2 skeys[181];
    if (threadIdx.x <= 180) {
        uint32_t x0 = 0u, x1 = (uint32_t)threadIdx.x;
        tf2x32(0u, 42u, x0, x1);
        skeys[threadIdx.x] = make_uint2(x0, x1);
    }
    __syncthreads();

    const int idx = blockIdx.x * 256 + threadIdx.x;
    const int b = idx >> 18;          // / HW
    const int p = idx & (HW - 1);

    // ---- ray setup (trajectory-critical: separate roundings preserved) ----
    // pixel_coords[b,y,x] = (x,y) exactly (meshgrid of arange; ints <= 511
    // are exact in fp32) -> int convert is bit-identical to the pix[] load.
    float px = (float)(p & (Wn - 1));
    float py = (float)(p >> 9);
    float v0 = (px - pp[b * 2 + 0]) / focal[b * 2 + 0];
    float v1 = (py - pp[b * 2 + 1]) / focal[b * 2 + 1];
    const float* R = rot + b * 9;
    float rdx = (R[0] * v0 + R[3] * v1) + R[6];
    float rdy = (R[1] * v0 + R[4] * v1) + R[7];
    float rdz = (R[2] * v0 + R[5] * v1) + R[8];
    float nrm = sqrtf((rdx * rdx + rdy * rdy) + rdz * rdz);
    rdx = rdx / nrm; rdy = rdy / nrm; rdz = rdz / nrm;
    float cpx = cpos[b * 3 + 0], cpy = cpos[b * 3 + 1], cpz = cpos[b * 3 + 2];

    float t1x = (-1.0f - cpx) / rdx, t2x = (1.0f - cpx) / rdx;
    float t1y = (-1.0f - cpy) / rdy, t2y = (1.0f - cpy) / rdy;
    float t1z = (-1.0f - cpz) / rdz, t2z = (1.0f - cpz) / rdz;
    float tmin = fmaxf(fminf(t1x, t2x), fmaxf(fminf(t1y, t2y), fminf(t1z, t2z)));
    float tmax = fminf(fmaxf(t1x, t2x), fminf(fmaxf(t1y, t2y), fmaxf(t1z, t2z)));
    bool hit = tmin < tmax;
    float t = fmaxf(hit ? tmin : 0.0f, 0.0f);

    // initial jitter: uniform [0,1) under fold_in(key,0), partitionable bits
    {
        uint2 k0 = skeys[0];
        uint32_t bits = pbits(k0.x, k0.y, (uint32_t)idx);
        float u = __uint_as_float(__builtin_amdgcn_alignbit(0x7fu, bits, 9u)) - 1.0f;
        u = fmaxf(0.0f, u);
        t = t - DTC * u;
    }

    float posx = cpx + rdx * t;
    float posy = cpy + rdy * t;
    float posz = cpz + rdz * t;

    float alpha = 0.0f, len = 0.0f;
    f2 acc_rg = {0.0f, 0.0f};
    float acc_b = 0.0f;
    bool entered = false;
    // A miss-ray only ever does len += step, identical to the tail body;
    // marking it done up-front lets all-miss waves skip the march loop
    // entirely (validated bit-exact).
    bool done = !hit;

    int i = 0;
    if (!__all(done)) {
        // Chunked march: 4 steps per chunk from 4 interleaved threefry
        // chains (ILP-4), early-exit at chunk boundaries (bit-exact: a done
        // ray's sub-step degenerates to the tail body, only len += step).
        const char* vbase = (const char*)(aos + (size_t)b * D3);
        const float* vol = tpl + (size_t)b * 4 * D3;
        while (i < NSTEP) {
            float s4[4];
            steps4(skeys[i + 1], skeys[i + 2], skeys[i + 3], skeys[i + 4],
                   (uint32_t)idx, s4);
            #pragma unroll
            for (int j = 0; j < 4; ++j) {
                float step = s4[j];
                float m = fmaxf(fmaxf(fabsf(posx), fabsf(posy)), fabsf(posz));
                bool valid = m < 1.0f;
                bool sampling = fmaxf(m, alpha) < 1.0f;

                float contrib = 0.0f;
                if (sampling) {
                    // pos in (-1,1) strictly => g in [0,127], no clamps needed
                    float gx = fmaf(posx, 63.5f, 63.5f);
                    float gy = fmaf(posy, 63.5f, 63.5f);
                    float gz = fmaf(posz, 63.5f, 63.5f);
                    float fx = floorf(gx), fy = floorf(gy), fz = floorf(gz);
                    float wx = gx - fx, wy = gy - fy, wz = gz - fz;
                    int ix0 = (int)fx, iy0 = (int)fy, iz0 = (int)fz;

                    float sx, sy, sz, sw;
                    if (PACKED) {
                        uint32_t xb  = (uint32_t)min(ix0, Dn - 2) << 4;
                        float wxe = (ix0 < Dn - 1) ? wx : 1.0f;
                        uint32_t yb0 = (uint32_t)iy0 << 11;
                        uint32_t yb1 = min(yb0 + (1u << 11), (uint32_t)(Dn - 1) << 11);
                        uint32_t zb0 = (uint32_t)iz0 << 18;
                        uint32_t zb1 = min(zb0 + (1u << 18), (uint32_t)(Dn - 1) << 18);

                        uint32_t o00 = zb0 + yb0 + xb;
                        uint32_t o01 = zb0 + yb1 + xb;
                        uint32_t o10 = zb1 + yb0 + xb;
                        uint32_t o11 = zb1 + yb1 + xb;

                        float4 A00 = *(const float4*)(vbase + o00);
                        float4 B00 = *(const float4*)(vbase + o00 + 16);
                        float4 A01 = *(const float4*)(vbase + o01);
                        float4 B01 = *(const float4*)(vbase + o01 + 16);
                        float4 A10 = *(const float4*)(vbase + o10);
                        float4 B10 = *(const float4*)(vbase + o10 + 16);
                        float4 A11 = *(const float4*)(vbase + o11);
                        float4 B11 = *(const float4*)(vbase + o11 + 16);

                        f2 wxv = {wxe, wxe}, wyv = {wy, wy}, wzv = {wz, wz};
                        f2 c00rg = plerp((f2){A00.x, A00.y}, (f2){B00.x, B00.y}, wxv);
                        f2 c00ba = plerp((f2){A00.z, A00.w}, (f2){B00.z, B00.w}, wxv);
                        f2 c01rg = plerp((f2){A01.x, A01.y}, (f2){B01.x, B01.y}, wxv);
                        f2 c01ba = plerp((f2){A01.z, A01.w}, (f2){B01.z, B01.w}, wxv);
                        f2 c10rg = plerp((f2){A10.x, A10.y}, (f2){B10.x, B10.y}, wxv);
                        f2 c10ba = plerp((f2){A10.z, A10.w}, (f2){B10.z, B10.w}, wxv);
                        f2 c11rg = plerp((f2){A11.x, A11.y}, (f2){B11.x, B11.y}, wxv);
                        f2 c11ba = plerp((f2){A11.z, A11.w}, (f2){B11.z, B11.w}, wxv);
                        f2 c0rg = plerp(c00rg, c01rg, wyv);
                        f2 c0ba = plerp(c00ba, c01ba, wyv);
                        f2 c1rg = plerp(c10rg, c11rg, wyv);
                        f2 c1ba = plerp(c10ba, c11ba, wyv);
                        f2 srg = plerp(c0rg, c1rg, wzv);
                        f2 sba = plerp(c0ba, c1ba, wzv);
                        sx = srg.x; sy = srg.y; sz = sba.x; sw = sba.y;
                    } else {
                        int ix1 = min(ix0 + 1, Dn - 1);
                        int iy1 = min(iy0 + 1, Dn - 1);
                        int iz1 = min(iz0 + 1, Dn - 1);
                        float owx = 1.0f - wx, owy = 1.0f - wy, owz = 1.0f - wz;
                        size_t o00 = ((size_t)iz0 * Dn + iy0) * Dn;
                        size_t o01 = ((size_t)iz0 * Dn + iy1) * Dn;
                        size_t o10 = ((size_t)iz1 * Dn + iy0) * Dn;
                        size_t o11 = ((size_t)iz1 * Dn + iy1) * Dn;
                        float s[4];
                        #pragma unroll
                        for (int c = 0; c < 4; ++c) {
                            const float* vc = vol + (size_t)c * D3;
                            float c00 = vc[o00 + ix0] * owx + vc[o00 + ix1] * wx;
                            float c01 = vc[o01 + ix0] * owx + vc[o01 + ix1] * wx;
                            float c10 = vc[o10 + ix0] * owx + vc[o10 + ix1] * wx;
                            float c11 = vc[o11 + ix0] * owx + vc[o11 + ix1] * wx;
                            float cc0 = c00 * owy + c01 * wy;
                            float cc1 = c10 * owy + c11 * wy;
                            s[c] = cc0 * owz + cc1 * wz;
                        }
                        sx = s[0]; sy = s[1]; sz = s[2]; sw = s[3];
                    }
                    contrib = fminf(fmaf(sw, step, alpha), 1.0f) - alpha;
                    f2 cv = {contrib, contrib};
                    acc_rg = __builtin_elementwise_fma((f2){sx, sy}, cv, acc_rg);
                    acc_b = fmaf(sz, contrib, acc_b);
                }
                alpha = alpha + contrib;
                if (contrib == 0.0f) len = len + step;
                posx = fmaf(rdx, step, posx);
                posy = fmaf(rdy, step, posy);
                posz = fmaf(rdz, step, posz);

                bool done_now = (alpha >= 1.0f) || (entered && !valid);
                entered = entered || valid;
                done = done || done_now;
            }
            i += 4;
            if (__all(done)) break;
        }
    }

    // tail: every remaining step has contrib == 0 -> only len accumulates.
    for (; i + 3 < NSTEP; i += 4) {
        float s4[4];
        steps4(skeys[i + 1], skeys[i + 2], skeys[i + 3], skeys[i + 4],
               (uint32_t)idx, s4);
        len = len + s4[0];
        len = len + s4[1];
        len = len + s4[2];
        len = len + s4[3];
    }
    for (; i < NSTEP; ++i) {
        uint2 kk = skeys[i + 1];
        len = len + step_from_bits(pbits(kk.x, kk.y, (uint32_t)idx));
    }

    // ---- epilogue: rgb + background blend, alpha, raw length ----
    size_t obase = (size_t)b * 3 * HW + p;
    out[obase]            = acc_rg.x + (1.0f - alpha) * fmaxf(bg[obase], 0.0f);
    out[obase + HW]       = acc_rg.y + (1.0f - alpha) * fmaxf(bg[obase + HW], 0.0f);
    out[obase + 2 * HW]   = acc_b   + (1.0f - alpha) * fmaxf(bg[obase + 2 * HW], 0.0f);
    out[(size_t)Bn * 3 * HW + (size_t)idx] = alpha;
    out[(size_t)Bn * 4 * HW + (size_t)idx] = len;

    // ---- block reduce min/max of len -> per-block slots (atomics-free) ----
    __shared__ float smax[256];
    __shared__ float smin[256];
    smax[threadIdx.x] = len;
    smin[threadIdx.x] = len;
    __syncthreads();
    for (int s = 128; s > 0; s >>= 1) {
        if (threadIdx.x < s) {
            smax[threadIdx.x] = fmaxf(smax[threadIdx.x], smax[threadIdx.x + s]);
            smin[threadIdx.x] = fminf(smin[threadIdx.x], smin[threadIdx.x + s]);
        }
        __syncthreads();
    }
    if (threadIdx.x == 0) {
        wsf[2 * blockIdx.x]     = smax[0];
        wsf[2 * blockIdx.x + 1] = smin[0];
    }
}

__global__ __launch_bounds__(256) void finalize_kernel(
    float* __restrict__ out, const float* __restrict__ wsf) {
    #pragma clang fp contract(off)
    // re-reduce the 2048 per-block (max,min) pairs (L2-resident, 16 KB)
    __shared__ float smax[256];
    __shared__ float smin[256];
    float mx = 0.0f;            // len >= 0
    float mn = 3.402823466e+38f;
    for (int j = threadIdx.x; j < NBLK; j += 256) {
        mx = fmaxf(mx, wsf[2 * j]);
        mn = fminf(mn, wsf[2 * j + 1]);
    }
    smax[threadIdx.x] = mx;
    smin[threadIdx.x] = mn;
    __syncthreads();
    for (int s = 128; s > 0; s >>= 1) {
        if (threadIdx.x < s) {
            smax[threadIdx.x] = fmaxf(smax[threadIdx.x], smax[threadIdx.x + s]);
            smin[threadIdx.x] = fminf(smin[threadIdx.x], smin[threadIdx.x + s]);
        }
        __syncthreads();
    }
    mx = smax[0];
    mn = smin[0];

    int i = blockIdx.x * 256 + threadIdx.x;
    if (i >= NRAY) return;
    float a = out[(size_t)Bn * 3 * HW + i];
    size_t loff = (size_t)Bn * 4 * HW + i;
    float l = out[loff];
    out[loff] = (a * l) / (mx + mn);
}

extern "C" void kernel_launch(void* const* d_in, const int* in_sizes, int n_in,
                              void* d_out, int out_size, void* d_ws, size_t ws_size,
                              hipStream_t stream) {
    const float* rot   = (const float*)d_in[0];
    const float* cpos  = (const float*)d_in[1];
    const float* focal = (const float*)d_in[2];
    const float* pp    = (const float*)d_in[3];
    // d_in[4] (pixel_coords) is reconstructed exactly on-device; unused.
    const float* tpl   = (const float*)d_in[5];
    const float* bg    = (const float*)d_in[6];
    float* out = (float*)d_out;
    float* wsf = (float*)d_ws;
    float4* aos = (float4*)((char*)d_ws + WS_AOS_BYTE_OFF);

    const bool packed = ws_size >= WS_AOS_BYTE_OFF + WS_AOS_BYTES;

    if (packed) {
        hipLaunchKernelGGL(repack_kernel, dim3((Bn * D3) / 256), dim3(256), 0,
                           stream, tpl, aos);
        hipLaunchKernelGGL(march_kernel<true>, dim3(NBLK), dim3(256), 0,
                           stream, rot, cpos, focal, pp, tpl, aos, bg, out, wsf);
    } else {
        hipLaunchKernelGGL(march_kernel<false>, dim3(NBLK), dim3(256), 0,
                           stream, rot, cpos, focal, pp, tpl, aos, bg, out, wsf);
    }
    hipLaunchKernelGGL(finalize_kernel, dim3(NRAY / 256), dim3(256), 0, stream,
                       out, wsf);
}